// Round 18
// baseline (131.272 us; speedup 1.0000x reference)
//
#include <hip/hip_runtime.h>
#include <math.h>

#define IN_DIM 16
#define HID 128
#define NEG 0.2f
#define ABLK 8192           // edges per block in bin pass
#define CAP 4608            // bucket capacity: mean 4096 + 8 sigma

__device__ __forceinline__ float lrelu(float a) { return a > 0.f ? a : NEG * a; }

// ---------------- K1: precompute (wave-parallel) + zero cursors ----
// M[dp][o] = sum_c W1[dp][c]·T[c][o],  C[o] = sum_c b1[c]·T[c][o]
// waves 0..319 -> M, 320..329 -> C, 330..361 -> wq1/wk1 rows.
__global__ void __launch_bounds__(256) k_pre(
    const float* __restrict__ W1, const float* __restrict__ q1, const float* __restrict__ k1,
    const float* __restrict__ b1, const float* __restrict__ W2, const float* __restrict__ q2,
    const float* __restrict__ k2,
    float* __restrict__ wq1, float* __restrict__ wk1,
    float* __restrict__ M, float* __restrict__ C,
    int* __restrict__ gCursor, int nbkt) {
    int zi = blockIdx.x * 256 + threadIdx.x;
    if (zi < nbkt) gCursor[zi] = 0;

    int w = blockIdx.x * 4 + (threadIdx.x >> 6);
    if (w >= 362) return;
    int lane = threadIdx.x & 63;

    auto T = [&](int c, int o) -> float {      // o is wave-uniform
        if (o < 3) return W2[c * 3 + o];
        if (o < 6) return W2[384 + c * 3 + (o - 3)];
        const float* base = (o == 6 || o == 8) ? (W2 + c * 3) : (W2 + 384 + c * 3);
        const float* v = (o < 8) ? q2 : k2;
        return base[0] * v[0] + base[1] * v[1] + base[2] * v[2];
    };

    if (w < 330) {
        bool isC = (w >= 320);
        int o  = isC ? (w - 320) : (w % 10);
        int dp = isC ? 0 : (w / 10);
        float acc = 0.f;
        for (int c = lane; c < HID; c += 64) {
            float left = isC ? b1[c] : W1[dp * HID + c];
            acc += left * T(c, o);
        }
#pragma unroll
        for (int off = 32; off; off >>= 1) acc += __shfl_xor(acc, off);
        if (lane == 0) { if (isC) C[o] = acc; else M[dp * 10 + o] = acc; }
    } else {
        int i = w - 330;                       // 0..31 = r*16+d
        float aq = 0.f, ak = 0.f;
        for (int c = lane; c < HID; c += 64) {
            float wv = W1[i * HID + c];
            aq += wv * q1[c]; ak += wv * k1[c];
        }
#pragma unroll
        for (int off = 32; off; off >>= 1) { aq += __shfl_xor(aq, off); ak += __shfl_xor(ak, off); }
        if (lane == 0) { wq1[i] = aq; wk1[i] = ak; }
    }
}

// ---------------- K2: bin edges into fixed-capacity buckets + scores
// binned[b*CAP + slot] = ((dst&255)<<17) | (et<<16) | src
__global__ void __launch_bounds__(256) k_bin(
    const int* __restrict__ srcp, const int* __restrict__ dstp,
    const int* __restrict__ etp,
    int* __restrict__ gCursor, int* __restrict__ binned,
    const float* __restrict__ x,
    const float* __restrict__ wq1, const float* __restrict__ wk1,
    float* __restrict__ sq1, float* __restrict__ sk1,
    int n_nodes, int ecnt, int nbkt) {
    __shared__ int lh[256];       // block-local bucket counts
    __shared__ int runB[256];     // reserved run base within bucket
    __shared__ float wq[2 * IN_DIM], wk[2 * IN_DIM];
    int t = threadIdx.x;
    lh[t] = 0;
    if (t < 2 * IN_DIM) { wq[t] = wq1[t]; wk[t] = wk1[t]; }
    __syncthreads();
    int E0 = blockIdx.x * ABLK;
    int rb[ABLK / 256];           // (rank<<8)|bucket per handled edge
#pragma unroll
    for (int k = 0; k < ABLK / 256; ++k) {
        int e = E0 + k * 256 + t;
        int v = -1;
        if (e < ecnt) {
            int b = dstp[e] >> 8;
            int r = atomicAdd(&lh[b], 1);
            v = (r << 8) | b;
        }
        rb[k] = v;
    }
    __syncthreads();
    if (t < nbkt && lh[t]) runB[t] = atomicAdd(&gCursor[t], lh[t]);
    __syncthreads();
#pragma unroll
    for (int k = 0; k < ABLK / 256; ++k) {
        int v = rb[k];
        if (v < 0) continue;
        int b = v & 255, r = v >> 8;
        int e = E0 + k * 256 + t;
        binned[b * CAP + runB[b] + r] = ((dstp[e] & 255) << 17) | (etp[e] << 16) | srcp[e];
    }
    // layer1 score scalars (node-parallel, grid-stride)
    int stride = gridDim.x * 256;
    for (int n = blockIdx.x * 256 + t; n < n_nodes; n += stride) {
        float q0 = 0.f, q1v = 0.f, k0 = 0.f, k1v = 0.f;
        const float4* xp = reinterpret_cast<const float4*>(x + (size_t)n * IN_DIM);
#pragma unroll
        for (int d4 = 0; d4 < IN_DIM / 4; ++d4) {
            float4 v = xp[d4];
            float vv[4] = {v.x, v.y, v.z, v.w};
#pragma unroll
            for (int j = 0; j < 4; ++j) {
                int d = d4 * 4 + j;
                q0 += vv[j] * wq[d]; q1v += vv[j] * wq[IN_DIM + d];
                k0 += vv[j] * wk[d]; k1v += vv[j] * wk[IN_DIM + d];
            }
        }
        sq1[n] = q0; sq1[n_nodes + n] = q1v;
        sk1[n] = k0; sk1[n_nodes + n] = k1v;
    }
}

// ---------------- K3: layer1 per-bucket LDS-atomic aggregation -----
// block = bucket; acc[dl][0..9]=numerators, [10]=denominator.
// finalize: o = acc/denom + C; empty node -> 0/1e-16=0 -> o=C (ref: h=b1). 
__global__ void __launch_bounds__(1024) k_agg1(
    const int* __restrict__ gCursor, const int* __restrict__ binned,
    const float* __restrict__ sq1, const float* __restrict__ sk1,
    const float* __restrict__ x, const float* __restrict__ M, const float* __restrict__ C,
    float* __restrict__ xr2p, float* __restrict__ sq2, int n_nodes) {
    __shared__ float Ml[320], Cl[10];
    __shared__ float sql[2][256];
    __shared__ float acc[256][13];   // stride 13: gcd(13,32)=1, all banks
    int t = threadIdx.x, b = blockIdx.x;
    for (int i = t; i < 320; i += 1024) Ml[i] = M[i];
    if (t < 10) Cl[t] = C[t];
    int nbase = b << 8;
    if (t < 512) {
        int r = t >> 8, dl = t & 255;
        int n = nbase + dl;
        sql[r][dl] = (n < n_nodes) ? sq1[r * n_nodes + n] : 0.f;
    }
    for (int i = t; i < 256 * 13; i += 1024) (&acc[0][0])[i] = 0.f;
    __syncthreads();
    int sz = gCursor[b];
    const float4* x4 = reinterpret_cast<const float4*>(x);
    for (int i = t; i < sz; i += 1024) {
        int v = binned[b * CAP + i];
        int dl = (v >> 17) & 255, et = (v >> 16) & 1, s = v & 0xFFFF;
        float w = __expf(lrelu(sql[et][dl] + sk1[et * n_nodes + s]));
        float4 xa = x4[s * 4 + 0], xb = x4[s * 4 + 1];
        float4 xc = x4[s * 4 + 2], xd = x4[s * 4 + 3];
        float xv[16] = {xa.x, xa.y, xa.z, xa.w, xb.x, xb.y, xb.z, xb.w,
                        xc.x, xc.y, xc.z, xc.w, xd.x, xd.y, xd.z, xd.w};
        const float* Mr = &Ml[et * 160];
        float* ab = acc[dl];
#pragma unroll
        for (int o = 0; o < 10; ++o) {
            float a = 0.f;
#pragma unroll
            for (int dd = 0; dd < 16; ++dd) a += xv[dd] * Mr[dd * 10 + o];
            atomicAdd(&ab[o], w * a);
        }
        atomicAdd(&ab[10], w);
    }
    __syncthreads();
    if (t < 256) {
        int n = nbase + t;
        if (n < n_nodes) {
            float inv = 1.f / (acc[t][10] + 1e-16f);
            float o[10];
#pragma unroll
            for (int i = 0; i < 10; ++i) o[i] = acc[t][i] * inv + Cl[i];
            reinterpret_cast<float4*>(xr2p)[n]           = make_float4(o[0], o[1], o[2], o[8]);
            reinterpret_cast<float4*>(xr2p)[n_nodes + n] = make_float4(o[3], o[4], o[5], o[9]);
            reinterpret_cast<float2*>(sq2)[n]            = make_float2(o[6], o[7]);
        }
    }
}

// ---------------- K4: layer2 per-bucket LDS-atomic aggregation -----
__global__ void __launch_bounds__(1024) k_agg2(
    const int* __restrict__ gCursor, const int* __restrict__ binned,
    const float* __restrict__ sq2, const float* __restrict__ xr2p,
    const float* __restrict__ b2, float* __restrict__ out, int n_nodes) {
    __shared__ float sql[256][2];
    __shared__ float acc[256][5];    // stride 5: gcd(5,32)=1
    __shared__ float b2l[3];
    int t = threadIdx.x, b = blockIdx.x;
    if (t < 3) b2l[t] = b2[t];
    int nbase = b << 8;
    if (t < 256) {
        int n = nbase + t;
        float2 s = (n < n_nodes) ? reinterpret_cast<const float2*>(sq2)[n]
                                 : make_float2(0.f, 0.f);
        sql[t][0] = s.x; sql[t][1] = s.y;
        acc[t][0] = acc[t][1] = acc[t][2] = acc[t][3] = 0.f;
    }
    __syncthreads();
    int sz = gCursor[b];
    for (int i = t; i < sz; i += 1024) {
        int v = binned[b * CAP + i];
        int dl = (v >> 17) & 255, et = (v >> 16) & 1, s = v & 0xFFFF;
        float4 xr = reinterpret_cast<const float4*>(xr2p)[(size_t)et * n_nodes + s];
        float w = __expf(lrelu(sql[dl][et] + xr.w));
        float* ab = acc[dl];
        atomicAdd(&ab[0], w * xr.x);
        atomicAdd(&ab[1], w * xr.y);
        atomicAdd(&ab[2], w * xr.z);
        atomicAdd(&ab[3], w);
    }
    __syncthreads();
    if (t < 256) {
        int n = nbase + t;
        if (n < n_nodes) {
            float inv = 1.f / (acc[t][3] + 1e-16f);
            out[(size_t)n * 3 + 0] = acc[t][0] * inv + b2l[0];
            out[(size_t)n * 3 + 1] = acc[t][1] * inv + b2l[1];
            out[(size_t)n * 3 + 2] = acc[t][2] * inv + b2l[2];
        }
    }
}

extern "C" void kernel_launch(void* const* d_in, const int* in_sizes, int n_in,
                              void* d_out, int out_size, void* d_ws, size_t ws_size,
                              hipStream_t stream) {
    const float* x  = (const float*)d_in[0];
    const int*   ei = (const int*)d_in[1];
    const int*   etp = (const int*)d_in[2];
    const float* W1 = (const float*)d_in[3];
    const float* q1 = (const float*)d_in[4];
    const float* k1 = (const float*)d_in[5];
    const float* b1 = (const float*)d_in[6];
    const float* W2 = (const float*)d_in[7];
    const float* q2 = (const float*)d_in[8];
    const float* k2 = (const float*)d_in[9];
    const float* b2 = (const float*)d_in[10];
    float* out = (float*)d_out;

    const int n_nodes = in_sizes[0] / IN_DIM;  // 50000
    const int ecnt    = in_sizes[2];           // 800000
    const int* srcp = ei;
    const int* dstp = ei + ecnt;
    const int nbkt = (n_nodes + 255) >> 8;     // 196

    char* wp = (char*)d_ws;
    auto alloc = [&](size_t bytes) -> char* {
        char* p = wp;
        wp += (bytes + 255) & ~(size_t)255;
        return p;
    };
    float* xr2p  = (float*)alloc((size_t)2 * n_nodes * 4 * 4);
    float* sq1   = (float*)alloc((size_t)2 * n_nodes * 4);
    float* sk1   = (float*)alloc((size_t)2 * n_nodes * 4);
    float* sq2   = (float*)alloc((size_t)2 * n_nodes * 4);
    float* wq1   = (float*)alloc(32 * 4);
    float* wk1   = (float*)alloc(32 * 4);
    float* Mbuf  = (float*)alloc(320 * 4);
    float* Cbuf  = (float*)alloc(10 * 4);
    int* gCursor = (int*)alloc(256 * 4);
    int* binned  = (int*)alloc((size_t)nbkt * CAP * 4);

    int nAblk = (ecnt + ABLK - 1) / ABLK;      // 98

    k_pre<<<91, 256, 0, stream>>>(W1, q1, k1, b1, W2, q2, k2, wq1, wk1, Mbuf, Cbuf,
                                  gCursor, nbkt);
    k_bin<<<nAblk, 256, 0, stream>>>(srcp, dstp, etp, gCursor, binned,
                                     x, wq1, wk1, sq1, sk1, n_nodes, ecnt, nbkt);
    k_agg1<<<nbkt, 1024, 0, stream>>>(gCursor, binned, sq1, sk1, x, Mbuf, Cbuf,
                                      xr2p, sq2, n_nodes);
    k_agg2<<<nbkt, 1024, 0, stream>>>(gCursor, binned, sq2, xr2p, b2, out, n_nodes);
}

// Round 19
// 97.634 us; speedup vs baseline: 1.3445x; 1.3445x over previous
//
#include <hip/hip_runtime.h>
#include <math.h>

#define IN_DIM 16
#define HID 128
#define NEG 0.2f
#define ABLK 8192           // edges per block in bin pass
#define CAP 4608            // bucket capacity: mean 4096 + 8 sigma

__device__ __forceinline__ float lrelu(float a) { return a > 0.f ? a : NEG * a; }

// ---------------- K1: precompute (wave-parallel) + zero cursors ----
__global__ void __launch_bounds__(256) k_pre(
    const float* __restrict__ W1, const float* __restrict__ q1, const float* __restrict__ k1,
    const float* __restrict__ b1, const float* __restrict__ W2, const float* __restrict__ q2,
    const float* __restrict__ k2,
    float* __restrict__ wq1, float* __restrict__ wk1,
    float* __restrict__ M, float* __restrict__ C,
    int* __restrict__ gCursor, int nbkt) {
    int zi = blockIdx.x * 256 + threadIdx.x;
    if (zi < nbkt) gCursor[zi] = 0;

    int w = blockIdx.x * 4 + (threadIdx.x >> 6);
    if (w >= 362) return;
    int lane = threadIdx.x & 63;

    auto T = [&](int c, int o) -> float {      // o is wave-uniform
        if (o < 3) return W2[c * 3 + o];
        if (o < 6) return W2[384 + c * 3 + (o - 3)];
        const float* base = (o == 6 || o == 8) ? (W2 + c * 3) : (W2 + 384 + c * 3);
        const float* v = (o < 8) ? q2 : k2;
        return base[0] * v[0] + base[1] * v[1] + base[2] * v[2];
    };

    if (w < 330) {
        bool isC = (w >= 320);
        int o  = isC ? (w - 320) : (w % 10);
        int dp = isC ? 0 : (w / 10);
        float acc = 0.f;
        for (int c = lane; c < HID; c += 64) {
            float left = isC ? b1[c] : W1[dp * HID + c];
            acc += left * T(c, o);
        }
#pragma unroll
        for (int off = 32; off; off >>= 1) acc += __shfl_xor(acc, off);
        if (lane == 0) { if (isC) C[o] = acc; else M[dp * 10 + o] = acc; }
    } else {
        int i = w - 330;                       // 0..31 = r*16+d
        float aq = 0.f, ak = 0.f;
        for (int c = lane; c < HID; c += 64) {
            float wv = W1[i * HID + c];
            aq += wv * q1[c]; ak += wv * k1[c];
        }
#pragma unroll
        for (int off = 32; off; off >>= 1) { aq += __shfl_xor(aq, off); ak += __shfl_xor(ak, off); }
        if (lane == 0) { wq1[i] = aq; wk1[i] = ak; }
    }
}

// ---------------- K2: bin edges into fixed-capacity buckets + scores
// binned[b*CAP + slot] = ((dst&255)<<17) | (et<<16) | src
__global__ void __launch_bounds__(256) k_bin(
    const int* __restrict__ srcp, const int* __restrict__ dstp,
    const int* __restrict__ etp,
    int* __restrict__ gCursor, int* __restrict__ binned,
    const float* __restrict__ x,
    const float* __restrict__ wq1, const float* __restrict__ wk1,
    float* __restrict__ sq1, float* __restrict__ sk1,
    int n_nodes, int ecnt, int nbkt) {
    __shared__ int lh[256];       // block-local bucket counts
    __shared__ int runB[256];     // reserved run base within bucket
    __shared__ float wq[2 * IN_DIM], wk[2 * IN_DIM];
    int t = threadIdx.x;
    lh[t] = 0;
    if (t < 2 * IN_DIM) { wq[t] = wq1[t]; wk[t] = wk1[t]; }
    __syncthreads();
    int E0 = blockIdx.x * ABLK;
    int rb[ABLK / 256];           // (rank<<8)|bucket per handled edge
#pragma unroll
    for (int k = 0; k < ABLK / 256; ++k) {
        int e = E0 + k * 256 + t;
        int v = -1;
        if (e < ecnt) {
            int b = dstp[e] >> 8;
            int r = atomicAdd(&lh[b], 1);
            v = (r << 8) | b;
        }
        rb[k] = v;
    }
    __syncthreads();
    if (t < nbkt && lh[t]) runB[t] = atomicAdd(&gCursor[t], lh[t]);
    __syncthreads();
#pragma unroll
    for (int k = 0; k < ABLK / 256; ++k) {
        int v = rb[k];
        if (v < 0) continue;
        int b = v & 255, r = v >> 8;
        int e = E0 + k * 256 + t;
        binned[b * CAP + runB[b] + r] = ((dstp[e] & 255) << 17) | (etp[e] << 16) | srcp[e];
    }
    // layer1 score scalars (node-parallel, grid-stride)
    int stride = gridDim.x * 256;
    for (int n = blockIdx.x * 256 + t; n < n_nodes; n += stride) {
        float q0 = 0.f, q1v = 0.f, k0 = 0.f, k1v = 0.f;
        const float4* xp = reinterpret_cast<const float4*>(x + (size_t)n * IN_DIM);
#pragma unroll
        for (int d4 = 0; d4 < IN_DIM / 4; ++d4) {
            float4 v = xp[d4];
            float vv[4] = {v.x, v.y, v.z, v.w};
#pragma unroll
            for (int j = 0; j < 4; ++j) {
                int d = d4 * 4 + j;
                q0 += vv[j] * wq[d]; q1v += vv[j] * wq[IN_DIM + d];
                k0 += vv[j] * wk[d]; k1v += vv[j] * wk[IN_DIM + d];
            }
        }
        sq1[n] = q0; sq1[n_nodes + n] = q1v;
        sk1[n] = k0; sk1[n_nodes + n] = k1v;
    }
}

// ---------------- K3: layer1 — in-LDS bucket build + gather agg ----
// block = bucket (1024 thr). Build: hist/scan/scatter into sortedL.
// Agg: R17's proven wave-per-node layout, sortedL read from LDS.
__global__ void __launch_bounds__(1024) k_l1(
    const int* __restrict__ gCursor, const int* __restrict__ binned,
    const float* __restrict__ sq1, const float* __restrict__ sk1,
    const float* __restrict__ x, const float* __restrict__ M, const float* __restrict__ C,
    float* __restrict__ xr2p, float* __restrict__ sq2, int n_nodes) {
    __shared__ float Ml[320], Cl[10];
    __shared__ int lh[256], loff[256], lcur[256], ss[256];
    __shared__ int sortedL[CAP];
    __shared__ float Al[16][32];
    int t = threadIdx.x, b = blockIdx.x;
    int nbase = b << 8;
    for (int i = t; i < 320; i += 1024) Ml[i] = M[i];
    if (t < 10) Cl[t] = C[t];
    if (t < 256) { lh[t] = 0; lcur[t] = 0; }
    __syncthreads();
    int sz = gCursor[b];
    // build phase 1: local-node histogram
    for (int i = t; i < sz; i += 1024)
        atomicAdd(&lh[(binned[b * CAP + i] >> 17) & 255], 1);
    __syncthreads();
    if (t < 256) ss[t] = lh[t];
    __syncthreads();
    for (int off = 1; off < 256; off <<= 1) {
        int u = (t >= off && t < 256) ? ss[t - off] : 0;
        __syncthreads();
        if (t < 256) ss[t] += u;
        __syncthreads();
    }
    if (t < 256) loff[t] = ss[t] - lh[t];
    __syncthreads();
    // build phase 2: scatter into sortedL
    for (int i = t; i < sz; i += 1024) {
        int v = binned[b * CAP + i];
        int dl = (v >> 17) & 255;
        int p = loff[dl] + atomicAdd(&lcur[dl], 1);
        sortedL[p] = v & 0x1FFFF;
    }
    __syncthreads();
    // aggregation: 16 waves x 16 nodes, R17 layout
    int wid = t >> 6, lane = t & 63;
    int ch4 = lane & 3, j = lane >> 2;
    const float4* x4 = reinterpret_cast<const float4*>(x);
    for (int g = 0; g < 16; ++g) {
        int dl = wid * 16 + g;
        int n = nbase + dl;
        if (n >= n_nodes) continue;        // wave-uniform
        int beg = loff[dl], end = beg + lh[dl];
        float s0 = sq1[n], s1 = sq1[n_nodes + n];
        float4 a0 = make_float4(0.f, 0.f, 0.f, 0.f);
        float4 a1 = make_float4(0.f, 0.f, 0.f, 0.f);
        float ds = 0.f;
        for (int e = beg + j; e < end; e += 16) {
            int pk = sortedL[e];
            int et = pk >> 16, s = pk & 0xFFFF;
            float w = __expf(lrelu((et ? s1 : s0) + sk1[et * n_nodes + s]));
            ds += w;
            float4 xv = x4[s * 4 + ch4];
            if (et == 0) { a0.x += w * xv.x; a0.y += w * xv.y; a0.z += w * xv.z; a0.w += w * xv.w; }
            else         { a1.x += w * xv.x; a1.y += w * xv.y; a1.z += w * xv.z; a1.w += w * xv.w; }
        }
#pragma unroll
        for (int off = 4; off <= 32; off <<= 1) {
            a0.x += __shfl_xor(a0.x, off); a0.y += __shfl_xor(a0.y, off);
            a0.z += __shfl_xor(a0.z, off); a0.w += __shfl_xor(a0.w, off);
            a1.x += __shfl_xor(a1.x, off); a1.y += __shfl_xor(a1.y, off);
            a1.z += __shfl_xor(a1.z, off); a1.w += __shfl_xor(a1.w, off);
            ds += __shfl_xor(ds, off);
        }
        float inv = 1.f / (ds + 1e-16f);
        if (lane < 4) {
            reinterpret_cast<float4*>(&Al[wid][0])[lane] =
                make_float4(a0.x * inv, a0.y * inv, a0.z * inv, a0.w * inv);
            reinterpret_cast<float4*>(&Al[wid][16])[lane] =
                make_float4(a1.x * inv, a1.y * inv, a1.z * inv, a1.w * inv);
        }
        // same-wave LDS write->read (compiler inserts lgkmcnt wait)
        if (lane < 10) {
            float acc = Cl[lane];
#pragma unroll
            for (int dp = 0; dp < 32; ++dp) acc += Al[wid][dp] * Ml[dp * 10 + lane];
            int o = lane;
            if (o < 3)       xr2p[(size_t)n * 4 + o] = acc;
            else if (o < 6)  xr2p[((size_t)n_nodes + n) * 4 + (o - 3)] = acc;
            else if (o == 6) sq2[2 * n] = acc;
            else if (o == 7) sq2[2 * n + 1] = acc;
            else if (o == 8) xr2p[(size_t)n * 4 + 3] = acc;               // sk2 r0
            else             xr2p[((size_t)n_nodes + n) * 4 + 3] = acc;   // sk2 r1
        }
    }
}

// ---------------- K4: layer2 — in-LDS bucket build + gather agg ----
// 16-lane groups: each wave handles 4 nodes/iter, 4 iters = 16 nodes.
__global__ void __launch_bounds__(1024) k_l2(
    const int* __restrict__ gCursor, const int* __restrict__ binned,
    const float* __restrict__ sq2, const float* __restrict__ xr2p,
    const float* __restrict__ b2, float* __restrict__ out, int n_nodes) {
    __shared__ int lh[256], loff[256], lcur[256], ss[256];
    __shared__ int sortedL[CAP];
    __shared__ float b2l[3];
    int t = threadIdx.x, b = blockIdx.x;
    int nbase = b << 8;
    if (t < 3) b2l[t] = b2[t];
    if (t < 256) { lh[t] = 0; lcur[t] = 0; }
    __syncthreads();
    int sz = gCursor[b];
    for (int i = t; i < sz; i += 1024)
        atomicAdd(&lh[(binned[b * CAP + i] >> 17) & 255], 1);
    __syncthreads();
    if (t < 256) ss[t] = lh[t];
    __syncthreads();
    for (int off = 1; off < 256; off <<= 1) {
        int u = (t >= off && t < 256) ? ss[t - off] : 0;
        __syncthreads();
        if (t < 256) ss[t] += u;
        __syncthreads();
    }
    if (t < 256) loff[t] = ss[t] - lh[t];
    __syncthreads();
    for (int i = t; i < sz; i += 1024) {
        int v = binned[b * CAP + i];
        int dl = (v >> 17) & 255;
        int p = loff[dl] + atomicAdd(&lcur[dl], 1);
        sortedL[p] = v & 0x1FFFF;
    }
    __syncthreads();
    int wid = t >> 6, lane = t & 63;
    int l = lane & 15;
    const float4* xr4 = reinterpret_cast<const float4*>(xr2p);
    for (int g = 0; g < 4; ++g) {
        int dl = wid * 16 + g * 4 + (lane >> 4);
        int n = nbase + dl;
        bool valid = (n < n_nodes);
        int beg = loff[dl], end = beg + lh[dl];
        float2 sq = valid ? reinterpret_cast<const float2*>(sq2)[n] : make_float2(0.f, 0.f);
        float lsum = 0.f, a0 = 0.f, a1 = 0.f, a2 = 0.f;
        for (int e = beg + l; e < end; e += 16) {
            int pk = sortedL[e];
            int et = pk >> 16, s = pk & 0xFFFF;
            float4 xr = xr4[(size_t)et * n_nodes + s];
            float w = __expf(lrelu((et ? sq.y : sq.x) + xr.w));
            lsum += w;
            a0 += w * xr.x; a1 += w * xr.y; a2 += w * xr.z;
        }
#pragma unroll
        for (int off = 8; off; off >>= 1) {
            lsum += __shfl_xor(lsum, off);
            a0 += __shfl_xor(a0, off);
            a1 += __shfl_xor(a1, off);
            a2 += __shfl_xor(a2, off);
        }
        if (l == 0 && valid) {
            float inv = 1.f / (lsum + 1e-16f);
            out[(size_t)n * 3 + 0] = a0 * inv + b2l[0];
            out[(size_t)n * 3 + 1] = a1 * inv + b2l[1];
            out[(size_t)n * 3 + 2] = a2 * inv + b2l[2];
        }
    }
}

extern "C" void kernel_launch(void* const* d_in, const int* in_sizes, int n_in,
                              void* d_out, int out_size, void* d_ws, size_t ws_size,
                              hipStream_t stream) {
    const float* x  = (const float*)d_in[0];
    const int*   ei = (const int*)d_in[1];
    const int*   etp = (const int*)d_in[2];
    const float* W1 = (const float*)d_in[3];
    const float* q1 = (const float*)d_in[4];
    const float* k1 = (const float*)d_in[5];
    const float* b1 = (const float*)d_in[6];
    const float* W2 = (const float*)d_in[7];
    const float* q2 = (const float*)d_in[8];
    const float* k2 = (const float*)d_in[9];
    const float* b2 = (const float*)d_in[10];
    float* out = (float*)d_out;

    const int n_nodes = in_sizes[0] / IN_DIM;  // 50000
    const int ecnt    = in_sizes[2];           // 800000
    const int* srcp = ei;
    const int* dstp = ei + ecnt;
    const int nbkt = (n_nodes + 255) >> 8;     // 196

    char* wp = (char*)d_ws;
    auto alloc = [&](size_t bytes) -> char* {
        char* p = wp;
        wp += (bytes + 255) & ~(size_t)255;
        return p;
    };
    float* xr2p  = (float*)alloc((size_t)2 * n_nodes * 4 * 4);
    float* sq1   = (float*)alloc((size_t)2 * n_nodes * 4);
    float* sk1   = (float*)alloc((size_t)2 * n_nodes * 4);
    float* sq2   = (float*)alloc((size_t)2 * n_nodes * 4);
    float* wq1   = (float*)alloc(32 * 4);
    float* wk1   = (float*)alloc(32 * 4);
    float* Mbuf  = (float*)alloc(320 * 4);
    float* Cbuf  = (float*)alloc(10 * 4);
    int* gCursor = (int*)alloc(256 * 4);
    int* binned  = (int*)alloc((size_t)nbkt * CAP * 4);

    int nAblk = (ecnt + ABLK - 1) / ABLK;      // 98

    k_pre<<<91, 256, 0, stream>>>(W1, q1, k1, b1, W2, q2, k2, wq1, wk1, Mbuf, Cbuf,
                                  gCursor, nbkt);
    k_bin<<<nAblk, 256, 0, stream>>>(srcp, dstp, etp, gCursor, binned,
                                     x, wq1, wk1, sq1, sk1, n_nodes, ecnt, nbkt);
    k_l1<<<nbkt, 1024, 0, stream>>>(gCursor, binned, sq1, sk1, x, Mbuf, Cbuf,
                                    xr2p, sq2, n_nodes);
    k_l2<<<nbkt, 1024, 0, stream>>>(gCursor, binned, sq2, xr2p, b2, out, n_nodes);
}

// Round 20
// 92.540 us; speedup vs baseline: 1.4186x; 1.0551x over previous
//
#include <hip/hip_runtime.h>
#include <math.h>

#define IN_DIM 16
#define HID 128
#define NEG 0.2f
#define ABLK 8192           // edges per block in bin pass
#define CAP 4608            // bucket capacity: mean 4096 + 8 sigma

__device__ __forceinline__ float lrelu(float a) { return a > 0.f ? a : NEG * a; }

// ---------------- K1: precompute (wave-parallel) + zero cursors ----
// M[dp][o] = sum_c W1[dp][c]·T[c][o],  C[o] = sum_c b1[c]·T[c][o]
// waves 0..319 -> M, 320..329 -> C, 330..361 -> wq1/wk1 rows.
__global__ void __launch_bounds__(256) k_pre(
    const float* __restrict__ W1, const float* __restrict__ q1, const float* __restrict__ k1,
    const float* __restrict__ b1, const float* __restrict__ W2, const float* __restrict__ q2,
    const float* __restrict__ k2,
    float* __restrict__ wq1, float* __restrict__ wk1,
    float* __restrict__ M, float* __restrict__ C,
    int* __restrict__ gCursor, int nbkt) {
    int zi = blockIdx.x * 256 + threadIdx.x;
    if (zi < nbkt) gCursor[zi] = 0;

    int w = blockIdx.x * 4 + (threadIdx.x >> 6);
    if (w >= 362) return;
    int lane = threadIdx.x & 63;

    auto T = [&](int c, int o) -> float {      // o is wave-uniform
        if (o < 3) return W2[c * 3 + o];
        if (o < 6) return W2[384 + c * 3 + (o - 3)];
        const float* base = (o == 6 || o == 8) ? (W2 + c * 3) : (W2 + 384 + c * 3);
        const float* v = (o < 8) ? q2 : k2;
        return base[0] * v[0] + base[1] * v[1] + base[2] * v[2];
    };

    if (w < 330) {
        bool isC = (w >= 320);
        int o  = isC ? (w - 320) : (w % 10);
        int dp = isC ? 0 : (w / 10);
        float acc = 0.f;
        for (int c = lane; c < HID; c += 64) {
            float left = isC ? b1[c] : W1[dp * HID + c];
            acc += left * T(c, o);
        }
#pragma unroll
        for (int off = 32; off; off >>= 1) acc += __shfl_xor(acc, off);
        if (lane == 0) { if (isC) C[o] = acc; else M[dp * 10 + o] = acc; }
    } else {
        int i = w - 330;                       // 0..31 = r*16+d
        float aq = 0.f, ak = 0.f;
        for (int c = lane; c < HID; c += 64) {
            float wv = W1[i * HID + c];
            aq += wv * q1[c]; ak += wv * k1[c];
        }
#pragma unroll
        for (int off = 32; off; off >>= 1) { aq += __shfl_xor(aq, off); ak += __shfl_xor(ak, off); }
        if (lane == 0) { wq1[i] = aq; wk1[i] = ak; }
    }
}

// ---------------- K2: bin edges into fixed-capacity buckets + scores
// binned[b*CAP + slot] = ((dst&255)<<17) | (et<<16) | src
__global__ void __launch_bounds__(256) k_bin(
    const int* __restrict__ srcp, const int* __restrict__ dstp,
    const int* __restrict__ etp,
    int* __restrict__ gCursor, int* __restrict__ binned,
    const float* __restrict__ x,
    const float* __restrict__ wq1, const float* __restrict__ wk1,
    float* __restrict__ sq1, float* __restrict__ sk1,
    int n_nodes, int ecnt, int nbkt) {
    __shared__ int lh[256];       // block-local bucket counts
    __shared__ int runB[256];     // reserved run base within bucket
    __shared__ float wq[2 * IN_DIM], wk[2 * IN_DIM];
    int t = threadIdx.x;
    lh[t] = 0;
    if (t < 2 * IN_DIM) { wq[t] = wq1[t]; wk[t] = wk1[t]; }
    __syncthreads();
    int E0 = blockIdx.x * ABLK;
    int rb[ABLK / 256];           // (rank<<8)|bucket per handled edge
#pragma unroll
    for (int k = 0; k < ABLK / 256; ++k) {
        int e = E0 + k * 256 + t;
        int v = -1;
        if (e < ecnt) {
            int b = dstp[e] >> 8;
            int r = atomicAdd(&lh[b], 1);
            v = (r << 8) | b;
        }
        rb[k] = v;
    }
    __syncthreads();
    if (t < nbkt && lh[t]) runB[t] = atomicAdd(&gCursor[t], lh[t]);
    __syncthreads();
#pragma unroll
    for (int k = 0; k < ABLK / 256; ++k) {
        int v = rb[k];
        if (v < 0) continue;
        int b = v & 255, r = v >> 8;
        int e = E0 + k * 256 + t;
        binned[b * CAP + runB[b] + r] = ((dstp[e] & 255) << 17) | (etp[e] << 16) | srcp[e];
    }
    // layer1 score scalars (node-parallel, grid-stride)
    int stride = gridDim.x * 256;
    for (int n = blockIdx.x * 256 + t; n < n_nodes; n += stride) {
        float q0 = 0.f, q1v = 0.f, k0 = 0.f, k1v = 0.f;
        const float4* xp = reinterpret_cast<const float4*>(x + (size_t)n * IN_DIM);
#pragma unroll
        for (int d4 = 0; d4 < IN_DIM / 4; ++d4) {
            float4 v = xp[d4];
            float vv[4] = {v.x, v.y, v.z, v.w};
#pragma unroll
            for (int j = 0; j < 4; ++j) {
                int d = d4 * 4 + j;
                q0 += vv[j] * wq[d]; q1v += vv[j] * wq[IN_DIM + d];
                k0 += vv[j] * wk[d]; k1v += vv[j] * wk[IN_DIM + d];
            }
        }
        sq1[n] = q0; sq1[n_nodes + n] = q1v;
        sk1[n] = k0; sk1[n_nodes + n] = k1v;
    }
}

// ---------------- K3: per-bucket segment build ---------------------
// sizes come from gCursor; emits offsets[] + compact sorted[]
__global__ void __launch_bounds__(256) k_build(
    const int* __restrict__ gCursor, const int* __restrict__ binned,
    int* __restrict__ offsets, int* __restrict__ sorted,
    int n_nodes, int ecnt, int nbkt) {
    __shared__ int ss[256], lh[256], loff[256], lcur[256];
    int t = threadIdx.x, b = blockIdx.x;
    int gv = (t < nbkt) ? gCursor[t] : 0;
    ss[t] = gv;
    lh[t] = 0;
    __syncthreads();
    for (int off = 1; off < 256; off <<= 1) {
        int u = (t >= off) ? ss[t - off] : 0;
        __syncthreads();
        ss[t] += u;
        __syncthreads();
    }
    int sz = gCursor[b];
    int myStart = ss[b] - sz;     // exclusive prefix (uniform LDS read)
    __syncthreads();
    // phase 1: local-node histogram of this bucket
    for (int i = t; i < sz; i += 256) {
        int v = binned[b * CAP + i];
        atomicAdd(&lh[(v >> 17) & 255], 1);
    }
    __syncthreads();
    ss[t] = lh[t];
    __syncthreads();
    for (int off = 1; off < 256; off <<= 1) {
        int u = (t >= off) ? ss[t - off] : 0;
        __syncthreads();
        ss[t] += u;
        __syncthreads();
    }
    loff[t] = ss[t] - lh[t];
    lcur[t] = 0;
    __syncthreads();
    int node = b * 256 + t;
    if (node < n_nodes) offsets[node] = myStart + loff[t];
    if (b == nbkt - 1 && t == 0) offsets[n_nodes] = ecnt;
    // phase 2: scatter within bucket region (L2 write-combined)
    for (int i = t; i < sz; i += 256) {
        int v = binned[b * CAP + i];
        int dl = (v >> 17) & 255;
        int p = loff[dl] + atomicAdd(&lcur[dl], 1);
        sorted[myStart + p] = v & 0x1FFFF;
    }
}

// ---------------- layer1 fused: aggregate -> 10 outputs ------------
__global__ void __launch_bounds__(256) k_layer1(
    const int* __restrict__ offsets, const int* __restrict__ sorted,
    const float* __restrict__ sq1, const float* __restrict__ sk1,
    const float* __restrict__ x, const float* __restrict__ M, const float* __restrict__ C,
    float* __restrict__ xr2p, float* __restrict__ sq2,
    int n_nodes) {
    __shared__ float Ml[320], Cl[10];
    __shared__ float Al[4][32];
    for (int i = threadIdx.x; i < 320; i += 256) Ml[i] = M[i];
    if (threadIdx.x < 10)  Cl[threadIdx.x] = C[threadIdx.x];
    __syncthreads();
    int wid = threadIdx.x >> 6, lane = threadIdx.x & 63;
    int n = blockIdx.x * 4 + wid;
    if (n >= n_nodes) return;
    int beg = offsets[n], end = offsets[n + 1];
    float s0 = sq1[n], s1 = sq1[n_nodes + n];
    int ch4 = lane & 3, j = lane >> 2;
    float4 a0 = make_float4(0.f, 0.f, 0.f, 0.f);
    float4 a1 = make_float4(0.f, 0.f, 0.f, 0.f);
    float ds = 0.f;
    const float4* x4 = reinterpret_cast<const float4*>(x);
    for (int e = beg + j; e < end; e += 16) {
        int pk = sorted[e];
        int et = pk >> 16, s = pk & 0xFFFF;
        float w = __expf(lrelu((et ? s1 : s0) + sk1[et * n_nodes + s]));
        ds += w;
        float4 xv = x4[s * 4 + ch4];
        if (et == 0) { a0.x += w * xv.x; a0.y += w * xv.y; a0.z += w * xv.z; a0.w += w * xv.w; }
        else         { a1.x += w * xv.x; a1.y += w * xv.y; a1.z += w * xv.z; a1.w += w * xv.w; }
    }
#pragma unroll
    for (int off = 4; off <= 32; off <<= 1) {
        a0.x += __shfl_xor(a0.x, off); a0.y += __shfl_xor(a0.y, off);
        a0.z += __shfl_xor(a0.z, off); a0.w += __shfl_xor(a0.w, off);
        a1.x += __shfl_xor(a1.x, off); a1.y += __shfl_xor(a1.y, off);
        a1.z += __shfl_xor(a1.z, off); a1.w += __shfl_xor(a1.w, off);
        ds += __shfl_xor(ds, off);
    }
    float inv = 1.f / (ds + 1e-16f);
    if (lane < 4) {
        reinterpret_cast<float4*>(&Al[wid][0])[lane] =
            make_float4(a0.x * inv, a0.y * inv, a0.z * inv, a0.w * inv);
        reinterpret_cast<float4*>(&Al[wid][16])[lane] =
            make_float4(a1.x * inv, a1.y * inv, a1.z * inv, a1.w * inv);
    }
    if (lane < 10) {
        float acc = Cl[lane];
#pragma unroll
        for (int dp = 0; dp < 32; ++dp) acc += Al[wid][dp] * Ml[dp * 10 + lane];
        int o = lane;
        if (o < 3)       xr2p[(size_t)n * 4 + o] = acc;
        else if (o < 6)  xr2p[((size_t)n_nodes + n) * 4 + (o - 3)] = acc;
        else if (o == 6) sq2[2 * n] = acc;
        else if (o == 7) sq2[2 * n + 1] = acc;
        else if (o == 8) xr2p[(size_t)n * 4 + 3] = acc;               // sk2 r0
        else             xr2p[((size_t)n_nodes + n) * 4 + 3] = acc;   // sk2 r1
    }
}

// ---------------- layer2 aggregation (16 lanes/node, single pass) --
__global__ void __launch_bounds__(256) k_node2(
    const int* __restrict__ offsets, const int* __restrict__ sorted,
    const float* __restrict__ sq2, const float* __restrict__ xr2p,
    const float* __restrict__ b2, float* __restrict__ out,
    int n_nodes) {
    int gid = blockIdx.x * 256 + threadIdx.x;
    int n = gid >> 4;
    int l = threadIdx.x & 15;
    if (n >= n_nodes) return;
    int beg = offsets[n], end = offsets[n + 1];
    if (beg == end) {
        if (l < 3) out[(size_t)n * 3 + l] = b2[l];
        return;
    }
    const float2 sq = *reinterpret_cast<const float2*>(sq2 + 2 * n);
    float lsum = 0.f, a0 = 0.f, a1 = 0.f, a2 = 0.f;
    for (int e = beg + l; e < end; e += 16) {
        int pk = sorted[e];
        int et = pk >> 16, s = pk & 0xFFFF;
        const float4 xr = *reinterpret_cast<const float4*>(xr2p + ((size_t)et * n_nodes + s) * 4);
        float w = __expf(lrelu((et ? sq.y : sq.x) + xr.w));
        lsum += w;
        a0 += w * xr.x; a1 += w * xr.y; a2 += w * xr.z;
    }
#pragma unroll
    for (int off = 8; off; off >>= 1) {
        lsum += __shfl_xor(lsum, off);
        a0 += __shfl_xor(a0, off);
        a1 += __shfl_xor(a1, off);
        a2 += __shfl_xor(a2, off);
    }
    if (l == 0) {
        float inv = 1.f / (lsum + 1e-16f);
        out[(size_t)n * 3 + 0] = a0 * inv + b2[0];
        out[(size_t)n * 3 + 1] = a1 * inv + b2[1];
        out[(size_t)n * 3 + 2] = a2 * inv + b2[2];
    }
}

extern "C" void kernel_launch(void* const* d_in, const int* in_sizes, int n_in,
                              void* d_out, int out_size, void* d_ws, size_t ws_size,
                              hipStream_t stream) {
    const float* x  = (const float*)d_in[0];
    const int*   ei = (const int*)d_in[1];
    const int*   etp = (const int*)d_in[2];
    const float* W1 = (const float*)d_in[3];
    const float* q1 = (const float*)d_in[4];
    const float* k1 = (const float*)d_in[5];
    const float* b1 = (const float*)d_in[6];
    const float* W2 = (const float*)d_in[7];
    const float* q2 = (const float*)d_in[8];
    const float* k2 = (const float*)d_in[9];
    const float* b2 = (const float*)d_in[10];
    float* out = (float*)d_out;

    const int n_nodes = in_sizes[0] / IN_DIM;  // 50000
    const int ecnt    = in_sizes[2];           // 800000
    const int* srcp = ei;
    const int* dstp = ei + ecnt;
    const int nbkt = (n_nodes + 255) >> 8;     // 196

    char* wp = (char*)d_ws;
    auto alloc = [&](size_t bytes) -> char* {
        char* p = wp;
        wp += (bytes + 255) & ~(size_t)255;
        return p;
    };
    float* xr2p  = (float*)alloc((size_t)2 * n_nodes * 4 * 4);
    float* sq1   = (float*)alloc((size_t)2 * n_nodes * 4);
    float* sk1   = (float*)alloc((size_t)2 * n_nodes * 4);
    float* sq2   = (float*)alloc((size_t)2 * n_nodes * 4);
    float* wq1   = (float*)alloc(32 * 4);
    float* wk1   = (float*)alloc(32 * 4);
    float* Mbuf  = (float*)alloc(320 * 4);
    float* Cbuf  = (float*)alloc(10 * 4);
    int* gCursor = (int*)alloc(256 * 4);
    int* offsets = (int*)alloc((size_t)(n_nodes + 1) * 4);
    int* binned  = (int*)alloc((size_t)nbkt * CAP * 4);
    int* sorted  = (int*)alloc((size_t)ecnt * 4);

    int nAblk = (ecnt + ABLK - 1) / ABLK;      // 98

    k_pre<<<91, 256, 0, stream>>>(W1, q1, k1, b1, W2, q2, k2, wq1, wk1, Mbuf, Cbuf,
                                  gCursor, nbkt);
    k_bin<<<nAblk, 256, 0, stream>>>(srcp, dstp, etp, gCursor, binned,
                                     x, wq1, wk1, sq1, sk1, n_nodes, ecnt, nbkt);
    k_build<<<nbkt, 256, 0, stream>>>(gCursor, binned, offsets, sorted, n_nodes, ecnt, nbkt);

    k_layer1<<<(n_nodes + 3) / 4, 256, 0, stream>>>(offsets, sorted, sq1, sk1, x, Mbuf, Cbuf,
                                                    xr2p, sq2, n_nodes);
    k_node2<<<(n_nodes * 16 + 255) / 256, 256, 0, stream>>>(offsets, sorted, sq2, xr2p, b2,
                                                            out, n_nodes);
}